// Round 1
// baseline (153.653 us; speedup 1.0000x reference)
//
#include <hip/hip_runtime.h>
#include <math.h>

// Problem constants (fixed by setup_inputs)
constexpr int B = 32;
constexpr int N = 65;   // seq_len + 1
constexpr int D = 512;
constexpr int S = 64;   // N - 1
constexpr int M = B * N; // 2080 rows for the QK projection GEMM

// ---------------------------------------------------------------------------
// K1: q = nve @ Wq^T + bq  (stored [B*N, D] row-major)
//     k = nve @ Wk^T + bk  (stored TRANSPOSED per batch: kT[b][d][n], n<N)
// Tiled fp32 GEMM, BM=64 BN=64 BK=32, 256 threads, 4x4 microtile per thread,
// q and k share the A (nve) tile.
// ---------------------------------------------------------------------------
#define BM 64
#define BN 64
#define BK 32

__global__ __launch_bounds__(256) void qk_gemm(
    const float* __restrict__ nve, const float* __restrict__ Wq,
    const float* __restrict__ bq, const float* __restrict__ Wk,
    const float* __restrict__ bk, float* __restrict__ q, float* __restrict__ kT)
{
    __shared__ float As[BK][BM + 1];
    __shared__ float Qs[BK][BN + 1];
    __shared__ float Ks[BK][BN + 1];

    const int bm = blockIdx.x * BM;
    const int bn = blockIdx.y * BN;
    const int tid = threadIdx.x;
    const int tr = tid / 16;   // 0..15 (row group)
    const int tc = tid % 16;   // 0..15 (col group)

    float accq[4][4] = {};
    float acck[4][4] = {};

    for (int k0 = 0; k0 < D; k0 += BK) {
        // Load A tile: 64 rows x 32 cols; 8 threads per row (float4 each), 2 passes
        {
            const int r  = tid / 8;          // 0..31
            const int c4 = (tid % 8) * 4;    // 0..28
            for (int p = 0; p < 2; ++p) {
                const int rr = p * 32 + r;
                const int gm = bm + rr;
                float4 v = make_float4(0.f, 0.f, 0.f, 0.f);
                if (gm < M) v = *(const float4*)&nve[(size_t)gm * D + k0 + c4];
                As[c4 + 0][rr] = v.x; As[c4 + 1][rr] = v.y;
                As[c4 + 2][rr] = v.z; As[c4 + 3][rr] = v.w;
            }
            for (int p = 0; p < 2; ++p) {
                const int rr = p * 32 + r;
                const int gn = bn + rr;      // always < D (512 % 64 == 0)
                float4 vq = *(const float4*)&Wq[(size_t)gn * D + k0 + c4];
                float4 vk = *(const float4*)&Wk[(size_t)gn * D + k0 + c4];
                Qs[c4 + 0][rr] = vq.x; Qs[c4 + 1][rr] = vq.y;
                Qs[c4 + 2][rr] = vq.z; Qs[c4 + 3][rr] = vq.w;
                Ks[c4 + 0][rr] = vk.x; Ks[c4 + 1][rr] = vk.y;
                Ks[c4 + 2][rr] = vk.z; Ks[c4 + 3][rr] = vk.w;
            }
        }
        __syncthreads();

        #pragma unroll
        for (int kk = 0; kk < BK; ++kk) {
            float a[4], wq_[4], wk_[4];
            #pragma unroll
            for (int u = 0; u < 4; ++u) a[u]   = As[kk][tr * 4 + u];
            #pragma unroll
            for (int u = 0; u < 4; ++u) wq_[u] = Qs[kk][tc * 4 + u];
            #pragma unroll
            for (int u = 0; u < 4; ++u) wk_[u] = Ks[kk][tc * 4 + u];
            #pragma unroll
            for (int i = 0; i < 4; ++i)
                #pragma unroll
                for (int j = 0; j < 4; ++j) {
                    accq[i][j] += a[i] * wq_[j];
                    acck[i][j] += a[i] * wk_[j];
                }
        }
        __syncthreads();
    }

    // Store: q row-major; k transposed per batch (for coalesced attn reads)
    #pragma unroll
    for (int i = 0; i < 4; ++i) {
        const int gm = bm + tr * 4 + i;
        if (gm >= M) continue;
        const int b = gm / N;
        const int n = gm % N;
        #pragma unroll
        for (int j = 0; j < 4; ++j) {
            const int gd = bn + tc * 4 + j;
            q[(size_t)gm * D + gd] = accq[i][j] + bq[gd];
            kT[(size_t)b * D * N + (size_t)gd * N + n] = acck[i][j] + bk[gd];
        }
    }
}

// ---------------------------------------------------------------------------
// K2: per (b, i) with i in 1..64: scores over all 65 columns, masked diag
// (score[i][i] = 0 pre-softmax), softmax, member bits = (prob>0.05)|eye.
// One block of 128 threads per row. Member mask packed via wave-0 __ballot.
// ---------------------------------------------------------------------------
__global__ __launch_bounds__(128) void attn_members(
    const float* __restrict__ q, const float* __restrict__ kT,
    unsigned long long* __restrict__ mem)
{
    const int bi = blockIdx.x;     // 0..B*S-1
    const int b = bi / S;
    const int r = bi % S;          // row index in member space
    const int i = r + 1;           // attn row index
    const int t = threadIdx.x;

    __shared__ float qrow[D];
    __shared__ float sc[N];

    // stage q[b, i, :] (128 threads x float4 = 512 floats)
    *(float4*)&qrow[t * 4] = *(const float4*)&q[((size_t)b * N + i) * D + t * 4];
    __syncthreads();

    if (t < N) {
        const float* kp = &kT[(size_t)b * D * N];
        float acc = 0.f;
        for (int e = 0; e < D; ++e) acc += qrow[e] * kp[(size_t)e * N + t];
        float s = acc * 0.044194173824159216f;  // 1/sqrt(512)
        if (t == i) s = 0.f;                    // no_self_loop mask (pre-softmax)
        sc[t] = s;
    }
    __syncthreads();

    if (t < 64) {  // wave 0: lane t handles member column j = t+1
        float mx = -INFINITY;
        for (int j = 0; j < N; ++j) mx = fmaxf(mx, sc[j]);
        float sum = 0.f;
        for (int j = 0; j < N; ++j) sum += expf(sc[j] - mx);
        const float p = expf(sc[t + 1] - mx) / sum;
        const bool bit = (p > 0.05f) || (t + 1 == i);
        unsigned long long mask = __ballot(bit);
        if (t == 0) mem[bi] = mask;
    }
}

// ---------------------------------------------------------------------------
// K3: greedy sequential clustering — one thread per batch, pure bit ops.
// ---------------------------------------------------------------------------
__global__ void cluster(const unsigned long long* __restrict__ mem,
                        unsigned long long* __restrict__ sel,
                        unsigned long long* __restrict__ lead)
{
    const int b = blockIdx.x * blockDim.x + threadIdx.x;
    if (b >= B) return;
    unsigned long long used = 0ull, lb = 0ull;
    for (int i = 0; i < S; ++i) {
        const unsigned long long row = mem[b * S + i];  // includes self bit
        const bool active = !((used >> i) & 1ull);
        const unsigned long long sl = active ? row : 0ull;
        used |= sl;
        lb |= (unsigned long long)active << i;
        sel[b * S + i] = sl;
    }
    lead[b] = lb;
}

// ---------------------------------------------------------------------------
// K4: dense output fill: out[b,i,0,:] = leader*cls, out[b,i,1+j,:] = sel*nve.
// Grid-stride over float4s; write-bound (~273 MB).
// ---------------------------------------------------------------------------
__global__ __launch_bounds__(256) void fill_out(
    const float* __restrict__ nve, const float* __restrict__ cls,
    const unsigned long long* __restrict__ sel,
    const unsigned long long* __restrict__ lead,
    float* __restrict__ out)
{
    const int total = B * S * (S + 1) * (D / 4);   // 17,039,360
    for (int idx = blockIdx.x * blockDim.x + threadIdx.x; idx < total;
         idx += gridDim.x * blockDim.x) {
        const int d4 = idx % (D / 4);
        const int t1 = idx / (D / 4);
        const int s  = t1 % (S + 1);
        const int t2 = t1 / (S + 1);
        const int i  = t2 % S;
        const int b  = t2 / S;

        bool on;
        const float* src;
        if (s == 0) {
            on  = (lead[b] >> i) & 1ull;
            src = &cls[d4 * 4];
        } else {
            on  = (sel[b * S + i] >> (s - 1)) & 1ull;
            src = &nve[((size_t)b * N + s) * D + d4 * 4];
        }
        float4 v = make_float4(0.f, 0.f, 0.f, 0.f);
        if (on) v = *(const float4*)src;
        *(float4*)&out[(size_t)idx * 4] = v;
    }
}

// ---------------------------------------------------------------------------
// K5: leader [B,S] and member [B,S,S] float outputs.
// ---------------------------------------------------------------------------
__global__ __launch_bounds__(256) void fill_lm(
    const unsigned long long* __restrict__ sel,
    const unsigned long long* __restrict__ lead,
    float* __restrict__ outl, float* __restrict__ outm)
{
    const int idx = blockIdx.x * blockDim.x + threadIdx.x;
    if (idx < B * S) {
        const int b = idx / S, i = idx % S;
        outl[idx] = (float)((lead[b] >> i) & 1ull);
    }
    if (idx < B * S * S) {
        const int b = idx / (S * S);
        const int rem = idx % (S * S);
        const int i = rem / S, j = rem % S;
        outm[idx] = (float)((sel[b * S + i] >> j) & 1ull);
    }
}

extern "C" void kernel_launch(void* const* d_in, const int* in_sizes, int n_in,
                              void* d_out, int out_size, void* d_ws, size_t ws_size,
                              hipStream_t stream) {
    // inputs: 0=desc(unused) 1=nve 2=Wq 3=bq 4=Wk 5=bk 6=cls
    const float* nve = (const float*)d_in[1];
    const float* Wq  = (const float*)d_in[2];
    const float* bq  = (const float*)d_in[3];
    const float* Wk  = (const float*)d_in[4];
    const float* bk  = (const float*)d_in[5];
    const float* cls = (const float*)d_in[6];

    float* out = (float*)d_out;

    // q and kT are staged INSIDE d_out (68M floats; q+kT need only 2.1M) —
    // fill_out overwrites all of d_out afterwards and never reads q/kT.
    float* q  = out;                       // M*D floats
    float* kT = q + (size_t)M * D;         // B*D*N floats

    // small bitmask scratch in d_ws (~33 KB)
    unsigned long long* mem  = (unsigned long long*)d_ws;       // B*S
    unsigned long long* sel  = mem + B * S;                     // B*S
    unsigned long long* lead = sel + B * S;                     // B

    dim3 g1((M + BM - 1) / BM, D / BN);   // (33, 8)
    qk_gemm<<<g1, 256, 0, stream>>>(nve, Wq, bq, Wk, bk, q, kT);

    attn_members<<<B * S, 128, 0, stream>>>(q, kT, mem);

    cluster<<<1, 64, 0, stream>>>(mem, sel, lead);

    fill_out<<<2048, 256, 0, stream>>>(nve, cls, sel, lead, out);

    float* outl = out + (size_t)B * S * (S + 1) * D;
    float* outm = outl + B * S;
    fill_lm<<<(B * S * S + 255) / 256, 256, 0, stream>>>(sel, lead, outl, outm);
}

// Round 2
// 108.889 us; speedup vs baseline: 1.4111x; 1.4111x over previous
//
#include <hip/hip_runtime.h>
#include <math.h>

// Problem constants (fixed by setup_inputs)
constexpr int B = 32;
constexpr int N = 65;    // seq_len + 1
constexpr int D = 512;
constexpr int S = 64;    // N - 1
constexpr int M = B * N; // 2080 rows for the QK projection GEMM

// out0 layout: [B, S, S+1, D] = 68,157,440 floats. The b=31 block
// (last 2,129,920 floats) is EXACTLY q (M*D) + kT (B*D*N) — we stage q/kT
// there, zero-fill b<31 concurrently, and densely rewrite b=31 at the end.
constexpr size_t OUT0_ELEMS = (size_t)B * S * (S + 1) * D;       // 68,157,440
constexpr size_t Q_ELEMS    = (size_t)M * D;                      // 1,064,960
constexpr size_t KT_ELEMS   = (size_t)B * D * N;                  // 1,064,960
constexpr size_t STAGE_BASE = OUT0_ELEMS - Q_ELEMS - KT_ELEMS;    // == b31 start
constexpr int ZF4 = (int)(STAGE_BASE / 4);                        // 16,506,880 float4 zeros

// K1 grid split
constexpr int NG_GEMM = 528;   // 33 m-tiles x 8 n-tiles x 2 matrices
constexpr int NG_FILL = 1536;
// K4 grid split
constexpr int NC = (B - 1) * S;            // 1984 scatter blocks (b<31)
constexpr int NA = 1040;                   // b31 dense fill: 1040*512 f4 = 532,480
constexpr int NB = 130;                    // leader+member: 130*256 f4 = 33,280

// ---------------------------------------------------------------------------
// K1: fused projection GEMM (q = nve@Wq^T+bq row-major; kT[b][d][n]) plus
// zero-fill of out0[b<31]. GEMM: 64x64 tile, BK=32, 256 thr, 4x4 microtile.
// ---------------------------------------------------------------------------
__global__ __launch_bounds__(256) void k1_gemm_fill(
    const float* __restrict__ nve, const float* __restrict__ Wq,
    const float* __restrict__ bq, const float* __restrict__ Wk,
    const float* __restrict__ bk, float* __restrict__ out)
{
    __shared__ float As[32][68];  // stride 68 floats = 272B (16B aligned)
    __shared__ float Ws[32][68];

    const int gid = blockIdx.x;
    const int tid = threadIdx.x;

    if (gid < NG_GEMM) {
        const int mat = gid >= (NG_GEMM / 2);
        const int t   = mat ? gid - NG_GEMM / 2 : gid;
        const int bm  = (t % 33) * 64;
        const int bn  = (t / 33) * 64;
        const float* W    = mat ? Wk : Wq;
        const float* bias = mat ? bk : bq;

        float* q  = out + STAGE_BASE;            // [M][D]
        float* kT = q + Q_ELEMS;                 // [B][D][N]

        const int tr = tid / 16;   // 0..15
        const int tc = tid % 16;   // 0..15
        float acc[4][4] = {};

        for (int k0 = 0; k0 < D; k0 += 32) {
            const int r  = tid / 8;          // 0..31
            const int c4 = (tid % 8) * 4;    // 0,4,..,28
            #pragma unroll
            for (int p = 0; p < 2; ++p) {
                const int rr = p * 32 + r;
                const int gm = bm + rr;
                float4 v = make_float4(0.f, 0.f, 0.f, 0.f);
                if (gm < M) v = *(const float4*)&nve[(size_t)gm * D + k0 + c4];
                As[c4 + 0][rr] = v.x; As[c4 + 1][rr] = v.y;
                As[c4 + 2][rr] = v.z; As[c4 + 3][rr] = v.w;
                float4 w = *(const float4*)&W[(size_t)(bn + rr) * D + k0 + c4];
                Ws[c4 + 0][rr] = w.x; Ws[c4 + 1][rr] = w.y;
                Ws[c4 + 2][rr] = w.z; Ws[c4 + 3][rr] = w.w;
            }
            __syncthreads();

            #pragma unroll
            for (int kk = 0; kk < 32; ++kk) {
                float a[4], w[4];
                #pragma unroll
                for (int u = 0; u < 4; ++u) a[u] = As[kk][tr * 4 + u];
                #pragma unroll
                for (int u = 0; u < 4; ++u) w[u] = Ws[kk][tc * 4 + u];
                #pragma unroll
                for (int i = 0; i < 4; ++i)
                    #pragma unroll
                    for (int j = 0; j < 4; ++j)
                        acc[i][j] += a[i] * w[j];
            }
            __syncthreads();
        }

        #pragma unroll
        for (int i = 0; i < 4; ++i) {
            const int gm = bm + tr * 4 + i;
            if (gm >= M) continue;
            const int b = gm / N;
            const int n = gm % N;
            if (mat == 0) {
                float4 v;
                v.x = acc[i][0] + bias[bn + tc * 4 + 0];
                v.y = acc[i][1] + bias[bn + tc * 4 + 1];
                v.z = acc[i][2] + bias[bn + tc * 4 + 2];
                v.w = acc[i][3] + bias[bn + tc * 4 + 3];
                *(float4*)&q[(size_t)gm * D + bn + tc * 4] = v;
            } else {
                #pragma unroll
                for (int j = 0; j < 4; ++j) {
                    const int gd = bn + tc * 4 + j;
                    kT[(size_t)b * D * N + (size_t)gd * N + n] = acc[i][j] + bias[gd];
                }
            }
        }
    } else {
        // zero-fill out0[b < 31] (float4 grid-stride)
        const float4 z = make_float4(0.f, 0.f, 0.f, 0.f);
        float4* o4 = (float4*)out;
        const int nthr = NG_FILL * 256;
        for (int f = (gid - NG_GEMM) * 256 + tid; f < ZF4; f += nthr)
            o4[f] = z;
    }
}

// ---------------------------------------------------------------------------
// K2: per (b,i), i in 1..64: scores over 65 cols (diag of [1:,1:] zeroed
// pre-softmax), softmax, member bits = (prob > 0.05) | eye -> 64-bit mask.
// ---------------------------------------------------------------------------
__global__ __launch_bounds__(128) void k2_attn(
    const float* __restrict__ out, unsigned long long* __restrict__ mem)
{
    const float* q  = out + STAGE_BASE;
    const float* kT = q + Q_ELEMS;

    const int bi = blockIdx.x;     // 0..B*S-1
    const int b = bi / S;
    const int r = bi % S;
    const int i = r + 1;
    const int t = threadIdx.x;

    __shared__ float qrow[D];
    __shared__ float sc[N];

    *(float4*)&qrow[t * 4] = *(const float4*)&q[((size_t)b * N + i) * D + t * 4];
    __syncthreads();

    if (t < N) {
        const float* kp = &kT[(size_t)b * D * N];
        float acc = 0.f;
        for (int e = 0; e < D; ++e) acc += qrow[e] * kp[(size_t)e * N + t];
        float s = acc * 0.044194173824159216f;  // 1/sqrt(512)
        if (t == i) s = 0.f;
        sc[t] = s;
    }
    __syncthreads();

    if (t < 64) {
        float mx = -INFINITY;
        for (int j = 0; j < N; ++j) mx = fmaxf(mx, sc[j]);
        float sum = 0.f;
        for (int j = 0; j < N; ++j) sum += expf(sc[j] - mx);
        const float p = expf(sc[t + 1] - mx) / sum;
        const bool bit = (p > 0.05f) || (t + 1 == i);
        unsigned long long mask = __ballot(bit);
        if (t == 0) mem[bi] = mask;
    }
}

// ---------------------------------------------------------------------------
// K3: greedy sequential clustering — one thread per batch.
// ---------------------------------------------------------------------------
__global__ void k3_cluster(const unsigned long long* __restrict__ mem,
                           unsigned long long* __restrict__ sel,
                           unsigned long long* __restrict__ lead)
{
    const int b = threadIdx.x;
    if (b >= B) return;
    unsigned long long used = 0ull, lb = 0ull;
    for (int i = 0; i < S; ++i) {
        const unsigned long long row = mem[b * S + i];
        const bool active = !((used >> i) & 1ull);
        const unsigned long long sl = active ? row : 0ull;
        used |= sl;
        lb |= (unsigned long long)active << i;
        sel[b * S + i] = sl;
    }
    lead[b] = lb;
}

// ---------------------------------------------------------------------------
// K4: (C) scatter nonzero rows for b<31; (A) dense bit-gated fill of the
// b=31 block (overwrites the q/kT staging); (B) leader/member outputs.
// ---------------------------------------------------------------------------
__global__ __launch_bounds__(256) void k4_finish(
    const float* __restrict__ nve, const float* __restrict__ cls,
    const unsigned long long* __restrict__ sel,
    const unsigned long long* __restrict__ lead,
    float* __restrict__ out)
{
    const int gid = blockIdx.x;
    const int t = threadIdx.x;

    if (gid < NC) {
        // scatter for b in [0,31): one block per (b,i) row
        const int b = gid / S;
        const int i = gid % S;
        const unsigned long long lb = lead[b];
        const unsigned long long sb = sel[b * S + i];
        const int h = t >> 7;          // 0/1: two columns in parallel
        const int tt = t & 127;        // f4 index within a 512-float slot
        float4* slot0 = (float4*)(out + (((size_t)b * S + i) * (S + 1)) * D);
        for (int s = h; s <= S; s += 2) {
            bool on = (s == 0) ? ((lb >> i) & 1ull) : ((sb >> (s - 1)) & 1ull);
            if (!on) continue;
            const float* src = (s == 0) ? cls : &nve[((size_t)b * N + s) * D];
            slot0[(size_t)s * 128 + tt] = ((const float4*)src)[tt];
        }
    } else if (gid < NC + NA) {
        // dense fill of b=31 region: 532,480 f4, 512 per block
        const int ablk = gid - NC;
        const unsigned long long lb = lead[B - 1];
        float4* base4 = (float4*)out + STAGE_BASE / 4;
        #pragma unroll
        for (int u = 0; u < 2; ++u) {
            const int f = ablk * 512 + u * 256 + t;
            const int d4 = f & 127;
            const int slot = f >> 7;         // 0..4159
            const int s = slot % (S + 1);
            const int i = slot / (S + 1);
            bool on;
            const float* src;
            if (s == 0) {
                on = (lb >> i) & 1ull;
                src = &cls[d4 * 4];
            } else {
                on = (sel[(B - 1) * S + i] >> (s - 1)) & 1ull;
                src = &nve[((size_t)(B - 1) * N + s) * D + d4 * 4];
            }
            float4 v = make_float4(0.f, 0.f, 0.f, 0.f);
            if (on) v = *(const float4*)src;
            base4[f] = v;
        }
    } else {
        // leader [B,S] then member [B,S,S] floats, f4-stored
        const int f = (gid - NC - NA) * 256 + t;   // f4 index
        float* tail = out + OUT0_ELEMS;
        float4 v;
        #pragma unroll
        for (int c = 0; c < 4; ++c) {
            const int idx = f * 4 + c;
            float x;
            if (idx < B * S) {
                x = (float)((lead[idx / S] >> (idx % S)) & 1ull);
            } else {
                const int m = idx - B * S;   // < B*S*S
                const int b = m / (S * S);
                const int rem = m % (S * S);
                x = (float)((sel[b * S + rem / S] >> (rem % S)) & 1ull);
            }
            ((float*)&v)[c] = x;
        }
        *(float4*)&tail[(size_t)f * 4] = v;
    }
}

extern "C" void kernel_launch(void* const* d_in, const int* in_sizes, int n_in,
                              void* d_out, int out_size, void* d_ws, size_t ws_size,
                              hipStream_t stream) {
    // inputs: 0=desc(unused) 1=nve 2=Wq 3=bq 4=Wk 5=bk 6=cls
    const float* nve = (const float*)d_in[1];
    const float* Wq  = (const float*)d_in[2];
    const float* bq  = (const float*)d_in[3];
    const float* Wk  = (const float*)d_in[4];
    const float* bk  = (const float*)d_in[5];
    const float* cls = (const float*)d_in[6];

    float* out = (float*)d_out;

    // small bitmask scratch in d_ws (~33 KB)
    unsigned long long* mem  = (unsigned long long*)d_ws;       // B*S
    unsigned long long* sel  = mem + B * S;                     // B*S
    unsigned long long* lead = sel + B * S;                     // B

    k1_gemm_fill<<<NG_GEMM + NG_FILL, 256, 0, stream>>>(nve, Wq, bq, Wk, bk, out);
    k2_attn<<<B * S, 128, 0, stream>>>(out, mem);
    k3_cluster<<<1, 64, 0, stream>>>(mem, sel, lead);
    k4_finish<<<NC + NA + NB, 256, 0, stream>>>(nve, cls, sel, lead, out);
}